// Round 1
// baseline (233.079 us; speedup 1.0000x reference)
//
#include <hip/hip_runtime.h>

// Loss_8615704396494: masked L1 + 0.1 * bone-direction MSE over [B=128,T=1024,150] fp32.
// Memory-bound: 157.3 MB input read, scalar output. One thread per (b,t) row.

#define N_JOINTS 50
#define ROW_F 150            // floats per row
#define ROW_F2 75            // float2 per row

__global__ __launch_bounds__(256) void loss_kernel(
    const float* __restrict__ preds,
    const float* __restrict__ targets,
    float* __restrict__ out,
    int n_rows, float inv_count)
{
    const float EPS = 1e-8f;
    int row = blockIdx.x * blockDim.x + threadIdx.x;

    float l1 = 0.0f;
    float mse = 0.0f;

    if (row < n_rows) {
        const float2* p2 = reinterpret_cast<const float2*>(preds)   + (size_t)row * ROW_F2;
        const float2* t2 = reinterpret_cast<const float2*>(targets) + (size_t)row * ROW_F2;

        // Streaming state: previous joint (masked values + mask), joint 0 (masked values).
        float pm_prev[3], tm_prev[3], m_prev[3];
        float pm0[3], tm0[3];

        // Bone: src joint S (with its mask) -> dst joint D.
        // pd = (S-D)/(|S-D|+eps) * m_S componentwise; mse += (pd - td)^2, m in {0,1}.
        auto do_bone = [&](const float* pmS, const float* tmS, const float* mS,
                           const float* pmD, const float* tmD) {
            float dp[3], dt[3];
            float lp = 0.0f, lt = 0.0f;
#pragma unroll
            for (int c = 0; c < 3; ++c) {
                dp[c] = pmS[c] - pmD[c];
                dt[c] = tmS[c] - tmD[c];
                lp += dp[c] * dp[c];
                lt += dt[c] * dt[c];
            }
            float ip = 1.0f / (sqrtf(lp) + EPS);
            float it = 1.0f / (sqrtf(lt) + EPS);
#pragma unroll
            for (int c = 0; c < 3; ++c) {
                float d = (dp[c] * ip - dt[c] * it) * mS[c];
                mse += d * d;
            }
        };

        // 25 chunks of 6 floats = 2 joints each (float2-aligned: row stride 600 B).
        for (int k = 0; k < 25; ++k) {
            float2 ta = t2[3 * k + 0], tb = t2[3 * k + 1], tc = t2[3 * k + 2];
            float2 pa = p2[3 * k + 0], pb = p2[3 * k + 1], pc = p2[3 * k + 2];

            float tA[3] = { ta.x, ta.y, tb.x };
            float tB[3] = { tb.y, tc.x, tc.y };
            float pA[3] = { pa.x, pa.y, pb.x };
            float pB[3] = { pb.y, pc.x, pc.y };

            float mA[3], pmA[3], tmA[3];
            float mB[3], pmB[3], tmB[3];
#pragma unroll
            for (int c = 0; c < 3; ++c) {
                mA[c]  = (tA[c] != 0.0f) ? 1.0f : 0.0f;
                pmA[c] = pA[c] * mA[c];
                tmA[c] = tA[c] * mA[c];
                l1 += fabsf(pmA[c] - tmA[c]);
                mB[c]  = (tB[c] != 0.0f) ? 1.0f : 0.0f;
                pmB[c] = pB[c] * mB[c];
                tmB[c] = tB[c] * mB[c];
                l1 += fabsf(pmB[c] - tmB[c]);
            }

            if (k == 0) {
#pragma unroll
                for (int c = 0; c < 3; ++c) { pm0[c] = pmA[c]; tm0[c] = tmA[c]; }
            } else {
                // bone (2k-1): joint 2k-1 (prev) -> joint 2k (A)
                do_bone(pm_prev, tm_prev, m_prev, pmA, tmA);
            }
            // bone (2k): joint 2k (A) -> joint 2k+1 (B)
            do_bone(pmA, tmA, mA, pmB, tmB);

#pragma unroll
            for (int c = 0; c < 3; ++c) { pm_prev[c] = pmB[c]; tm_prev[c] = tmB[c]; m_prev[c] = mB[c]; }
        }
        // bone 49: joint 49 (prev) -> joint 0
        do_bone(pm_prev, tm_prev, m_prev, pm0, tm0);
    }

    // Combine and reduce: loss = l1/COUNT + 0.1*mse/COUNT (same COUNT = B*T*150).
    float part = (l1 + 0.1f * mse) * inv_count;

    // wave-64 reduction
#pragma unroll
    for (int off = 32; off > 0; off >>= 1)
        part += __shfl_down(part, off, 64);

    __shared__ float wsum[4];
    int lane = threadIdx.x & 63;
    int wid  = threadIdx.x >> 6;
    if (lane == 0) wsum[wid] = part;
    __syncthreads();
    if (threadIdx.x == 0) {
        float s = wsum[0] + wsum[1] + wsum[2] + wsum[3];
        atomicAdd(out, s);
    }
}

extern "C" void kernel_launch(void* const* d_in, const int* in_sizes, int n_in,
                              void* d_out, int out_size, void* d_ws, size_t ws_size,
                              hipStream_t stream)
{
    const float* preds   = (const float*)d_in[0];
    const float* targets = (const float*)d_in[1];
    float* out = (float*)d_out;

    // d_out is re-poisoned to 0xAA before every timed launch — zero it (capture-safe).
    hipMemsetAsync(out, 0, sizeof(float) * out_size, stream);

    int n_elems = in_sizes[0];            // 128*1024*150
    int n_rows  = n_elems / ROW_F;        // 131072
    float inv_count = 1.0f / (float)n_elems;

    int block = 256;
    int grid  = (n_rows + block - 1) / block;
    loss_kernel<<<grid, block, 0, stream>>>(preds, targets, out, n_rows, inv_count);
}

// Round 2
// 219.083 us; speedup vs baseline: 1.0639x; 1.0639x over previous
//
#include <hip/hip_runtime.h>

// Loss_8615704396494: masked L1 + 0.1 * bone-direction MSE over [B=128,T=1024,150] fp32.
// Memory-bound (157.3 MB read, scalar out). R2: LDS-staged, fully-coalesced float4
// global loads (R1 had 2.1x overfetch from L1 thrash with per-thread-row reads).
//
// Block = 256 threads = 32 rows. Stage 32x600B per array via linear float4 loads
// (span 19200 B is 16B-aligned). Compute: 8 chain segments/row, wave-uniform.

#define ROW_F   150
#define ROWS_PB 32
#define SPAN_F  (ROWS_PB * ROW_F)      // 4800 floats per array per block
#define SPAN_F4 (SPAN_F / 4)           // 1200 float4

__global__ __launch_bounds__(256, 4) void loss_kernel(
    const float* __restrict__ preds,
    const float* __restrict__ targets,
    float* __restrict__ out,
    float inv_count)
{
    const float EPS = 1e-8f;
    __shared__ float sp[SPAN_F];
    __shared__ float st[SPAN_F];

    const int tid = threadIdx.x;
    const size_t base = (size_t)blockIdx.x * SPAN_F;   // float offset of block span

    // ---- Stage: coalesced float4 loads, all in flight before LDS writes ----
    const float4* gp4 = reinterpret_cast<const float4*>(preds + base);
    const float4* gt4 = reinterpret_cast<const float4*>(targets + base);
    float4* sp4 = reinterpret_cast<float4*>(sp);
    float4* st4 = reinterpret_cast<float4*>(st);

    float4 rp[5], rt[5];
#pragma unroll
    for (int i = 0; i < 5; ++i) {
        int g = i * 256 + tid;
        if (g < SPAN_F4) { rp[i] = gp4[g]; rt[i] = gt4[g]; }
    }
#pragma unroll
    for (int i = 0; i < 5; ++i) {
        int g = i * 256 + tid;
        if (g < SPAN_F4) { sp4[g] = rp[i]; st4[g] = rt[i]; }
    }
    __syncthreads();

    // ---- Compute: seg = tid>>5 (wave-uniform), row = tid&31 ----
    const int seg = tid >> 5;          // 0..7
    const int row = tid & 31;          // 0..31
    // joint/bone segment boundaries: segs 0,1 -> 7 bones; segs 2..7 -> 6 bones
    const int j0 = (seg < 2) ? seg * 7 : 14 + (seg - 2) * 6;
    const int j1 = (seg < 2) ? j0 + 7  : j0 + 6;

    const float* rpb = sp + row * ROW_F;
    const float* rtb = st + row * ROW_F;

    float l1 = 0.0f, mse = 0.0f;

    // load joint j -> masked pred, masked target, mask (mask from target != 0)
    auto load_joint = [&](int j, float* pm, float* tm, float* m) {
#pragma unroll
        for (int c = 0; c < 3; ++c) {
            float t = rtb[3 * j + c];
            float p = rpb[3 * j + c];
            float mk = (t != 0.0f) ? 1.0f : 0.0f;
            m[c] = mk;
            pm[c] = p * mk;
            tm[c] = t;          // t * mk == t (mk==0 only when t==0)
        }
    };

    auto do_bone = [&](const float* pmS, const float* tmS, const float* mS,
                       const float* pmD, const float* tmD) {
        float dp[3], dt[3];
        float lp = 0.0f, lt = 0.0f;
#pragma unroll
        for (int c = 0; c < 3; ++c) {
            dp[c] = pmS[c] - pmD[c];
            dt[c] = tmS[c] - tmD[c];
            lp += dp[c] * dp[c];
            lt += dt[c] * dt[c];
        }
        float ip = 1.0f / (sqrtf(lp) + EPS);
        float it = 1.0f / (sqrtf(lt) + EPS);
#pragma unroll
        for (int c = 0; c < 3; ++c) {
            float d = (dp[c] * ip - dt[c] * it) * mS[c];
            mse += d * d;
        }
    };

    float pmP[3], tmP[3], mP[3];
    load_joint(j0, pmP, tmP, mP);
#pragma unroll
    for (int c = 0; c < 3; ++c) l1 += fabsf(pmP[c] - tmP[c]);

    for (int b = j0; b < j1; ++b) {
        int jn = b + 1;
        if (jn == 50) jn = 0;          // wrap (seg 7 last bone), wave-uniform
        float pmN[3], tmN[3], mN[3];
        load_joint(jn, pmN, tmN, mN);
        if (jn < j1 && jn != 0) {      // jn belongs to this segment -> its L1
#pragma unroll
            for (int c = 0; c < 3; ++c) l1 += fabsf(pmN[c] - tmN[c]);
        }
        do_bone(pmP, tmP, mP, pmN, tmN);
#pragma unroll
        for (int c = 0; c < 3; ++c) { pmP[c] = pmN[c]; tmP[c] = tmN[c]; mP[c] = mN[c]; }
    }

    // ---- Reduce: loss = (l1 + 0.1*mse) / COUNT ----
    float part = (l1 + 0.1f * mse) * inv_count;
#pragma unroll
    for (int off = 32; off > 0; off >>= 1)
        part += __shfl_down(part, off, 64);

    __shared__ float wsum[4];
    int lane = tid & 63;
    int wid  = tid >> 6;
    if (lane == 0) wsum[wid] = part;
    __syncthreads();
    if (tid == 0) {
        float s = wsum[0] + wsum[1] + wsum[2] + wsum[3];
        atomicAdd(out, s);
    }
}

extern "C" void kernel_launch(void* const* d_in, const int* in_sizes, int n_in,
                              void* d_out, int out_size, void* d_ws, size_t ws_size,
                              hipStream_t stream)
{
    const float* preds   = (const float*)d_in[0];
    const float* targets = (const float*)d_in[1];
    float* out = (float*)d_out;

    // d_out is re-poisoned to 0xAA before every timed launch — zero it (capture-safe).
    hipMemsetAsync(out, 0, sizeof(float) * out_size, stream);

    int n_elems = in_sizes[0];              // 128*1024*150 = 19,660,800
    int n_rows  = n_elems / ROW_F;          // 131072
    float inv_count = 1.0f / (float)n_elems;

    int grid = n_rows / ROWS_PB;            // 4096 blocks, exact
    loss_kernel<<<grid, 256, 0, stream>>>(preds, targets, out, inv_count);
}

// Round 3
// 184.257 us; speedup vs baseline: 1.2650x; 1.1890x over previous
//
#include <hip/hip_runtime.h>

// Loss_8615704396494: masked L1 + 0.1 * bone-direction MSE over [B=128,T=1024,150] fp32.
// Memory-bound (157.3 MB read, scalar out).
// R2 post-mortem: float4 staging arrays spilled to scratch -> 157 MB of HBM writeback.
// R3: global_load_lds DMA staging (no VGPR round-trip, no scratch).
//
// Block = 256 threads = 32 rows. Span per array = 19200 B = 1200 float4
// = 18 full wave-chunks (64 lanes x 16 B) + one 48-lane tail chunk.

#define ROW_F   150
#define ROWS_PB 32
#define SPAN_F  (ROWS_PB * ROW_F)      // 4800 floats per array per block
#define SPAN_F4 (SPAN_F / 4)           // 1200 float4
#define N_CHUNK 19                     // ceil(1200/64)

typedef const __attribute__((address_space(1))) float  gfloat;
typedef __attribute__((address_space(3))) float        lfloat;

__global__ __launch_bounds__(256, 4) void loss_kernel(
    const float* __restrict__ preds,
    const float* __restrict__ targets,
    float* __restrict__ out,
    float inv_count)
{
    const float EPS = 1e-8f;
    __shared__ float sp[SPAN_F];
    __shared__ float st[SPAN_F];

    const int tid  = threadIdx.x;
    const int lane = tid & 63;
    const int wid  = tid >> 6;
    const size_t base = (size_t)blockIdx.x * SPAN_F;   // float offset of block span

    // ---- Stage via direct global->LDS DMA (wave-uniform LDS base + lane*16) ----
    const float* gp = preds + base;
    const float* gt = targets + base;

    for (int c = wid; c < N_CHUNK; c += 4) {
        const int f4 = c * 64;                  // chunk's first float4 index
        if (f4 + lane < SPAN_F4) {              // exec-masks the 48-lane tail chunk
            __builtin_amdgcn_global_load_lds(
                (gfloat*)(gp + 4 * (f4 + lane)), (lfloat*)(sp + 4 * f4), 16, 0, 0);
            __builtin_amdgcn_global_load_lds(
                (gfloat*)(gt + 4 * (f4 + lane)), (lfloat*)(st + 4 * f4), 16, 0, 0);
        }
    }
    __syncthreads();   // drains vmcnt incl. LDS-DMA

    // ---- Compute: seg = tid>>5 (wave-uniform), row = tid&31 ----
    const int seg = tid >> 5;          // 0..7
    const int row = tid & 31;          // 0..31
    // segs 0,1 -> 7 bones/joints; segs 2..7 -> 6
    const int j0 = (seg < 2) ? seg * 7 : 14 + (seg - 2) * 6;
    const int j1 = (seg < 2) ? j0 + 7  : j0 + 6;

    const float* rpb = sp + row * ROW_F;
    const float* rtb = st + row * ROW_F;

    float l1 = 0.0f, mse = 0.0f;

    auto load_joint = [&](int j, float* pm, float* tm, float* m) {
#pragma unroll
        for (int c = 0; c < 3; ++c) {
            float t = rtb[3 * j + c];
            float p = rpb[3 * j + c];
            float mk = (t != 0.0f) ? 1.0f : 0.0f;
            m[c] = mk;
            pm[c] = p * mk;
            tm[c] = t;          // t * mk == t
        }
    };

    auto do_bone = [&](const float* pmS, const float* tmS, const float* mS,
                       const float* pmD, const float* tmD) {
        float dp[3], dt[3];
        float lp = 0.0f, lt = 0.0f;
#pragma unroll
        for (int c = 0; c < 3; ++c) {
            dp[c] = pmS[c] - pmD[c];
            dt[c] = tmS[c] - tmD[c];
            lp += dp[c] * dp[c];
            lt += dt[c] * dt[c];
        }
        float ip = 1.0f / (sqrtf(lp) + EPS);
        float it = 1.0f / (sqrtf(lt) + EPS);
#pragma unroll
        for (int c = 0; c < 3; ++c) {
            float d = (dp[c] * ip - dt[c] * it) * mS[c];
            mse += d * d;
        }
    };

    float pmP[3], tmP[3], mP[3];
    load_joint(j0, pmP, tmP, mP);
#pragma unroll
    for (int c = 0; c < 3; ++c) l1 += fabsf(pmP[c] - tmP[c]);

    for (int b = j0; b < j1; ++b) {
        int jn = b + 1;
        if (jn == 50) jn = 0;          // wrap (seg 7 last bone), wave-uniform
        float pmN[3], tmN[3], mN[3];
        load_joint(jn, pmN, tmN, mN);
        if (jn < j1 && jn != 0) {      // jn belongs to this segment -> its L1 term
#pragma unroll
            for (int c = 0; c < 3; ++c) l1 += fabsf(pmN[c] - tmN[c]);
        }
        do_bone(pmP, tmP, mP, pmN, tmN);
#pragma unroll
        for (int c = 0; c < 3; ++c) { pmP[c] = pmN[c]; tmP[c] = tmN[c]; mP[c] = mN[c]; }
    }

    // ---- Reduce: loss = (l1 + 0.1*mse) / COUNT ----
    float part = (l1 + 0.1f * mse) * inv_count;
#pragma unroll
    for (int off = 32; off > 0; off >>= 1)
        part += __shfl_down(part, off, 64);

    __shared__ float wsum[4];
    if (lane == 0) wsum[wid] = part;
    __syncthreads();
    if (tid == 0) {
        float s = wsum[0] + wsum[1] + wsum[2] + wsum[3];
        atomicAdd(out, s);
    }
}

extern "C" void kernel_launch(void* const* d_in, const int* in_sizes, int n_in,
                              void* d_out, int out_size, void* d_ws, size_t ws_size,
                              hipStream_t stream)
{
    const float* preds   = (const float*)d_in[0];
    const float* targets = (const float*)d_in[1];
    float* out = (float*)d_out;

    // d_out is re-poisoned to 0xAA before every timed launch — zero it (capture-safe).
    hipMemsetAsync(out, 0, sizeof(float) * out_size, stream);

    int n_elems = in_sizes[0];              // 128*1024*150 = 19,660,800
    int n_rows  = n_elems / ROW_F;          // 131072
    float inv_count = 1.0f / (float)n_elems;

    int grid = n_rows / ROWS_PB;            // 4096 blocks, exact
    loss_kernel<<<grid, 256, 0, stream>>>(preds, targets, out, inv_count);
}

// Round 4
// 176.310 us; speedup vs baseline: 1.3220x; 1.0451x over previous
//
#include <hip/hip_runtime.h>

// Loss_8615704396494: masked L1 + 0.1 * bone-direction MSE over [B=128,T=1024,150] fp32.
// Memory-bound (157.3 MB read, scalar out).
// R3 post-mortem: single-buffered stage->barrier->compute per 38KB block = stop-and-wait
// on DMA latency; HBM 1.1 TB/s, effective 2.3 TB/s.
// R4: persistent blocks (grid=512, 2/CU) + double-buffered global_load_lds pipeline.
// Barrier at iter top drains current buffer's DMA (issued one compute-phase earlier);
// next span's DMA is issued right after, so the memory system streams continuously.

#define ROW_F   150
#define ROWS_PB 32
#define SPAN_F  (ROWS_PB * ROW_F)      // 4800 floats per array per span
#define SPAN_F4 (SPAN_F / 4)           // 1200 float4
#define N_CHUNK 19                     // ceil(1200/64) wave-chunks

typedef const __attribute__((address_space(1))) float  gfloat;
typedef __attribute__((address_space(3))) float        lfloat;

__device__ __forceinline__ void load_joint(const float* __restrict__ rpb,
                                           const float* __restrict__ rtb,
                                           int j, float* pm, float* tm, float* m)
{
#pragma unroll
    for (int c = 0; c < 3; ++c) {
        float t = rtb[3 * j + c];
        float p = rpb[3 * j + c];
        float mk = (t != 0.0f) ? 1.0f : 0.0f;
        m[c] = mk;
        pm[c] = p * mk;
        tm[c] = t;          // t * mk == t (mk==0 only when t==0)
    }
}

__device__ __forceinline__ void do_bone(const float* pmS, const float* tmS, const float* mS,
                                        const float* pmD, const float* tmD, float& mse)
{
    const float EPS = 1e-8f;
    float dp[3], dt[3];
    float lp = 0.0f, lt = 0.0f;
#pragma unroll
    for (int c = 0; c < 3; ++c) {
        dp[c] = pmS[c] - pmD[c];
        dt[c] = tmS[c] - tmD[c];
        lp += dp[c] * dp[c];
        lt += dt[c] * dt[c];
    }
    float ip = 1.0f / (sqrtf(lp) + EPS);
    float it = 1.0f / (sqrtf(lt) + EPS);
#pragma unroll
    for (int c = 0; c < 3; ++c) {
        float d = (dp[c] * ip - dt[c] * it) * mS[c];
        mse += d * d;
    }
}

__global__ __launch_bounds__(256, 2) void loss_kernel(
    const float* __restrict__ preds,
    const float* __restrict__ targets,
    float* __restrict__ out,
    int iters, float inv_count)
{
    // double buffer: [buf][preds/targets][span]  = 2*2*19200 B = 76.8 KB -> 2 blocks/CU
    __shared__ float smem[2][2][SPAN_F];
    __shared__ float wsum[4];

    const int tid  = threadIdx.x;
    const int lane = tid & 63;
    const int wid  = tid >> 6;

    auto stage = [&](int span, int buf) {
        const float* gp = preds   + (size_t)span * SPAN_F;
        const float* gt = targets + (size_t)span * SPAN_F;
        float* bsp = smem[buf][0];
        float* bst = smem[buf][1];
        for (int c = wid; c < N_CHUNK; c += 4) {
            const int f4 = c * 64;                  // wave-uniform LDS base (per chunk)
            if (f4 + lane < SPAN_F4) {              // exec-masks the 48-lane tail chunk
                __builtin_amdgcn_global_load_lds(
                    (gfloat*)(gp + 4 * (f4 + lane)), (lfloat*)(bsp + 4 * f4), 16, 0, 0);
                __builtin_amdgcn_global_load_lds(
                    (gfloat*)(gt + 4 * (f4 + lane)), (lfloat*)(bst + 4 * f4), 16, 0, 0);
            }
        }
    };

    // compute mapping: seg = tid>>5 (wave-uniform), row = tid&31
    const int seg = tid >> 5;          // 0..7
    const int row = tid & 31;          // 0..31
    const int j0 = (seg < 2) ? seg * 7 : 14 + (seg - 2) * 6;   // segs 0,1: 7 bones; else 6
    const int j1 = (seg < 2) ? j0 + 7  : j0 + 6;

    float l1 = 0.0f, mse = 0.0f;

    stage(blockIdx.x, 0);   // prologue DMA

    for (int it = 0; it < iters; ++it) {
        __syncthreads();    // drains vmcnt(0): current buffer's DMA + prior compute done
        if (it + 1 < iters)
            stage(blockIdx.x + (it + 1) * gridDim.x, (it + 1) & 1);   // prefetch in flight

        const float* rpb = smem[it & 1][0] + row * ROW_F;
        const float* rtb = smem[it & 1][1] + row * ROW_F;

        float pmP[3], tmP[3], mP[3];
        load_joint(rpb, rtb, j0, pmP, tmP, mP);
#pragma unroll
        for (int c = 0; c < 3; ++c) l1 += fabsf(pmP[c] - tmP[c]);

        for (int b = j0; b < j1; ++b) {
            int jn = b + 1;
            if (jn == 50) jn = 0;          // wrap bone (seg 7), wave-uniform
            float pmN[3], tmN[3], mN[3];
            load_joint(rpb, rtb, jn, pmN, tmN, mN);
            if (jn < j1 && jn != 0) {      // jn inside this segment -> its L1 term
#pragma unroll
                for (int c = 0; c < 3; ++c) l1 += fabsf(pmN[c] - tmN[c]);
            }
            do_bone(pmP, tmP, mP, pmN, tmN, mse);
#pragma unroll
            for (int c = 0; c < 3; ++c) { pmP[c] = pmN[c]; tmP[c] = tmN[c]; mP[c] = mN[c]; }
        }
    }

    // ---- Reduce: loss = (l1 + 0.1*mse) / COUNT ----
    float part = (l1 + 0.1f * mse) * inv_count;
#pragma unroll
    for (int off = 32; off > 0; off >>= 1)
        part += __shfl_down(part, off, 64);

    if (lane == 0) wsum[wid] = part;
    __syncthreads();
    if (tid == 0) {
        float s = wsum[0] + wsum[1] + wsum[2] + wsum[3];
        atomicAdd(out, s);
    }
}

extern "C" void kernel_launch(void* const* d_in, const int* in_sizes, int n_in,
                              void* d_out, int out_size, void* d_ws, size_t ws_size,
                              hipStream_t stream)
{
    const float* preds   = (const float*)d_in[0];
    const float* targets = (const float*)d_in[1];
    float* out = (float*)d_out;

    // d_out is re-poisoned to 0xAA before every timed launch — zero it (capture-safe).
    hipMemsetAsync(out, 0, sizeof(float) * out_size, stream);

    int n_elems = in_sizes[0];              // 128*1024*150 = 19,660,800
    int n_rows  = n_elems / ROW_F;          // 131072
    int spans   = n_rows / ROWS_PB;         // 4096
    float inv_count = 1.0f / (float)n_elems;

    int grid  = 512;                        // 2 persistent blocks per CU (LDS-bounded)
    int iters = spans / grid;               // 8
    loss_kernel<<<grid, 256, 0, stream>>>(preds, targets, out, iters, inv_count);
}

// Round 5
// 175.637 us; speedup vs baseline: 1.3271x; 1.0038x over previous
//
#include <hip/hip_runtime.h>

// Loss_8615704396494: masked L1 + 0.1 * bone-direction MSE over [B=128,T=1024,150] fp32.
// Memory-bound (157.3 MB read, scalar out).
// R4 post-mortem: global_load_lds + barrier(vmcnt(0)) locksteps all 8 waves/CU ->
// latency-serialized, 2.4 TB/s effective.
// R5: m97-style mainloop — register prefetch (named float4 locals, clamped idx, no
// spillable arrays) -> ds_write -> barrier -> issue next prefetch -> compute.
// Prefetch DMA overlaps compute; compiler's vmcnt(0)-at-barrier is the wait we need
// anyway before ds_write. 4 blocks/CU (38.4 KB LDS), persistent grid=1024, iters=4.
// VALU cut: v_sqrt/v_rcp intrinsics instead of refined sqrtf / exact div.

#define ROW_F    150
#define ROWS_PB  32
#define SPAN_F   (ROWS_PB * ROW_F)     // 4800 floats per array per span
#define SPAN_F4  (SPAN_F / 4)          // 1200 float4
#define GRID     1024

__global__ __launch_bounds__(256, 4) void loss_kernel(
    const float* __restrict__ preds,
    const float* __restrict__ targets,
    float* __restrict__ out,
    int iters, float inv_count)
{
    const float EPS = 1e-8f;
    __shared__ float sp[SPAN_F];
    __shared__ float st[SPAN_F];
    __shared__ float wsum[4];

    const int tid  = threadIdx.x;
    const int lane = tid & 63;
    const int wid  = tid >> 6;

    const float4* gp4 = reinterpret_cast<const float4*>(preds);
    const float4* gt4 = reinterpret_cast<const float4*>(targets);
    float4* sp4 = reinterpret_cast<float4*>(sp);
    float4* st4 = reinterpret_cast<float4*>(st);

    // Per-thread float4 slots: 4 full + 1 tail. Loads use clamped index (uniform
    // control flow -> named locals stay in VGPRs); stores guard the tail.
    const int g0 = tid, g1 = tid + 256, g2 = tid + 512, g3 = tid + 768, g4 = tid + 1024;
    const bool w4 = (g4 < SPAN_F4);
    const int g4c = w4 ? g4 : (SPAN_F4 - 1);

    // Compute mapping: seg = tid>>5 (wave-uniform), row = tid&31.
    const int seg = tid >> 5;          // 0..7
    const int row = tid & 31;          // 0..31
    const int j0 = (seg < 2) ? seg * 7 : 14 + (seg - 2) * 6;   // segs 0,1: 7 bones; else 6
    const int j1 = (seg < 2) ? j0 + 7  : j0 + 6;

    float l1 = 0.0f, mse = 0.0f;

    // Prologue prefetch: span = blockIdx.x
    size_t sb = (size_t)blockIdx.x * SPAN_F4;
    float4 rp0 = gp4[sb + g0], rp1 = gp4[sb + g1], rp2 = gp4[sb + g2],
           rp3 = gp4[sb + g3], rp4 = gp4[sb + g4c];
    float4 rt0 = gt4[sb + g0], rt1 = gt4[sb + g1], rt2 = gt4[sb + g2],
           rt3 = gt4[sb + g3], rt4 = gt4[sb + g4c];

    for (int it = 0; it < iters; ++it) {
        if (it) __syncthreads();            // readers of LDS buffer done

        // regs -> LDS (vmcnt waits for the prefetch happen here / at barrier above)
        sp4[g0] = rp0; st4[g0] = rt0;
        sp4[g1] = rp1; st4[g1] = rt1;
        sp4[g2] = rp2; st4[g2] = rt2;
        sp4[g3] = rp3; st4[g3] = rt3;
        if (w4) { sp4[g4] = rp4; st4[g4] = rt4; }
        __syncthreads();                    // writes visible to all waves

        if (it + 1 < iters) {               // issue next span's loads; in flight during compute
            size_t nb = (size_t)(blockIdx.x + (size_t)(it + 1) * GRID) * SPAN_F4;
            rp0 = gp4[nb + g0]; rp1 = gp4[nb + g1]; rp2 = gp4[nb + g2];
            rp3 = gp4[nb + g3]; rp4 = gp4[nb + g4c];
            rt0 = gt4[nb + g0]; rt1 = gt4[nb + g1]; rt2 = gt4[nb + g2];
            rt3 = gt4[nb + g3]; rt4 = gt4[nb + g4c];
        }

        // ---- Compute this span from LDS ----
        const float* rpb = sp + row * ROW_F;
        const float* rtb = st + row * ROW_F;

        float pmP[3], tmP[3];
#pragma unroll
        for (int c = 0; c < 3; ++c) {
            float t = rtb[3 * j0 + c];
            float p = rpb[3 * j0 + c];
            pmP[c] = (t != 0.0f) ? p : 0.0f;   // masked pred
            tmP[c] = t;                        // masked target == target
            l1 += fabsf(pmP[c] - tmP[c]);
        }

        for (int b = j0; b < j1; ++b) {
            int jn = b + 1;
            if (jn == 50) jn = 0;              // wrap bone (seg 7), wave-uniform
            float pmN[3], tmN[3];
#pragma unroll
            for (int c = 0; c < 3; ++c) {
                float t = rtb[3 * jn + c];
                float p = rpb[3 * jn + c];
                pmN[c] = (t != 0.0f) ? p : 0.0f;
                tmN[c] = t;
            }
            if (jn < j1 && jn != 0) {          // jn owned by this segment -> its L1 term
#pragma unroll
                for (int c = 0; c < 3; ++c) l1 += fabsf(pmN[c] - tmN[c]);
            }
            // bone: src = P (mask from tmP), dst = N
            float dp[3], dt[3], lp = 0.0f, lt = 0.0f;
#pragma unroll
            for (int c = 0; c < 3; ++c) {
                dp[c] = pmP[c] - pmN[c];
                dt[c] = tmP[c] - tmN[c];
                lp += dp[c] * dp[c];
                lt += dt[c] * dt[c];
            }
            float ip = __builtin_amdgcn_rcpf(__builtin_amdgcn_sqrtf(lp) + EPS);
            float iq = __builtin_amdgcn_rcpf(__builtin_amdgcn_sqrtf(lt) + EPS);
#pragma unroll
            for (int c = 0; c < 3; ++c) {
                float d = dp[c] * ip - dt[c] * iq;
                d = (tmP[c] != 0.0f) ? d : 0.0f;   // source-joint mask
                mse += d * d;
            }
#pragma unroll
            for (int c = 0; c < 3; ++c) { pmP[c] = pmN[c]; tmP[c] = tmN[c]; }
        }
    }

    // ---- Reduce: loss = (l1 + 0.1*mse) / COUNT ----
    float part = (l1 + 0.1f * mse) * inv_count;
#pragma unroll
    for (int off = 32; off > 0; off >>= 1)
        part += __shfl_down(part, off, 64);

    if (lane == 0) wsum[wid] = part;
    __syncthreads();
    if (tid == 0) {
        float s = wsum[0] + wsum[1] + wsum[2] + wsum[3];
        atomicAdd(out, s);
    }
}

extern "C" void kernel_launch(void* const* d_in, const int* in_sizes, int n_in,
                              void* d_out, int out_size, void* d_ws, size_t ws_size,
                              hipStream_t stream)
{
    const float* preds   = (const float*)d_in[0];
    const float* targets = (const float*)d_in[1];
    float* out = (float*)d_out;

    // d_out is re-poisoned to 0xAA before every timed launch — zero it (capture-safe).
    hipMemsetAsync(out, 0, sizeof(float) * out_size, stream);

    int n_elems = in_sizes[0];              // 128*1024*150 = 19,660,800
    int n_rows  = n_elems / ROW_F;          // 131072
    int spans   = n_rows / ROWS_PB;         // 4096
    float inv_count = 1.0f / (float)n_elems;

    int iters = spans / GRID;               // 4
    loss_kernel<<<GRID, 256, 0, stream>>>(preds, targets, out, iters, inv_count);
}